// Round 2
// baseline (9249.896 us; speedup 1.0000x reference)
//
#include <hip/hip_runtime.h>
#include <math.h>

#define BT 65536      // batch rows
#define NIN 1024      // input dim (reduction)
#define KK 1024       // codes (logit cols)
#define EE 256        // embedding dim
#define MT 32         // rows per block
#define NB 256        // cols per col-block
#define NCB 4         // col-blocks
#define KB 32         // reduction chunk
#define LOGK 6.9314718055994531f

// LDS layouts (XOR-swizzled, no padding):
//   ws[n][col], n in 0..31, col in 0..255: sidx = n*256 + 4*((col>>2)^(n>>2)) + (col&3)
//   xs[n][row], n in 0..31, row in 0..31 : sidx = n*32  + 4*((row>>2)^(n>>2)) + (row&3)
// Inner-loop reads: lane tc reads cols {4tc..4tc+3} and {128+4tc..+3} -> contiguous
// 16B chunks per lane, XOR by (n>>2)<8 permutes aligned 8-lane groups onto full
// bank rows -> conflict-free b128. Staging stores land at 2-way aliasing (free).
__global__ __launch_bounds__(256, 2)
void vq_main(const float* __restrict__ x, const float* __restrict__ gum,
             const float* __restrict__ W, const float* __restrict__ bias,
             const float* __restrict__ cbk, float* __restrict__ out,
             float* __restrict__ gsum) {
    __shared__ float smem[KB * NB + KB * MT];   // 8192 + 1024 floats = 36 KB
    float* ws = smem;
    float* xs = smem + KB * NB;

    const int tid = threadIdx.x;
    const int tc = tid & 31;          // col thread: cols 4*tc, 128+4*tc per col-block
    const int tr = tid >> 5;          // row group: rows 4*tr..4*tr+3
    const int row0 = blockIdx.x * MT;

    // staging decomposition: 8 threads per row/col, 4-float n-chunks
    const int d    = tid & 7;         // n-subgroup (== (wn+q)>>2 for q<4)
    const int srow = tid >> 3;        // 0..31
    const int wn   = d << 2;          // 0,4,...,28

    // swizzled store bases
    const int xbase = wn * MT + 4 * ((srow >> 2) ^ d) + (srow & 3);
    const int wbase = wn * NB + 4 * ((tid >> 5) ^ d) + ((tid >> 3) & 3);

    float lg[4][32];                  // [row i][cb*8 + j]
    #pragma unroll
    for (int i = 0; i < 4; ++i)
        #pragma unroll
        for (int t = 0; t < 32; ++t) lg[i][t] = 0.f;

    // ---- prefetch first tiles (kc=0, cb=0) into registers
    const float* xp = x + (size_t)(row0 + srow) * NIN + wn;
    float4 xv = *(const float4*)xp;
    float4 wv[8];
    #pragma unroll
    for (int l = 0; l < 8; ++l)
        wv[l] = *(const float4*)(W + (size_t)(l * 32 + srow) * NIN + wn);

    for (int kc = 0; kc < NIN / KB; ++kc) {
        #pragma unroll
        for (int cb = 0; cb < NCB; ++cb) {
            if (cb == 0) {
                xs[xbase + 0 * MT] = xv.x;
                xs[xbase + 1 * MT] = xv.y;
                xs[xbase + 2 * MT] = xv.z;
                xs[xbase + 3 * MT] = xv.w;
            }
            #pragma unroll
            for (int l = 0; l < 8; ++l) {
                ws[wbase + l * 32 + 0 * NB] = wv[l].x;
                ws[wbase + l * 32 + 1 * NB] = wv[l].y;
                ws[wbase + l * 32 + 2 * NB] = wv[l].z;
                ws[wbase + l * 32 + 3 * NB] = wv[l].w;
            }
            __syncthreads();

            // prefetch next tile (registers only; latency hides under n-loop)
            if (cb < NCB - 1) {
                #pragma unroll
                for (int l = 0; l < 8; ++l)
                    wv[l] = *(const float4*)(W + (size_t)((cb + 1) * NB + l * 32 + srow) * NIN
                                             + kc * KB + wn);
            } else {
                const int nkc = (kc + 1) & (NIN / KB - 1);   // wraps on last iter (harmless)
                #pragma unroll
                for (int l = 0; l < 8; ++l)
                    wv[l] = *(const float4*)(W + (size_t)(l * 32 + srow) * NIN + nkc * KB + wn);
                xv = *(const float4*)(xp + nkc * KB);
            }

            // inner compute: g runtime (keeps code small), 4 n per g unrolled
            for (int g = 0; g < 8; ++g) {
                const int xo = g * 128 + 4 * (tr ^ g);   // g*4*MT
                const int wo = g * 1024 + 4 * (tc ^ g);  // g*4*NB
                #pragma unroll
                for (int q = 0; q < 4; ++q) {
                    const float4 a  = *(const float4*)(xs + xo + q * MT);
                    const float4 b0 = *(const float4*)(ws + wo + q * NB);
                    const float4 b1 = *(const float4*)(ws + wo + q * NB + 128);
                    const float av[4] = {a.x, a.y, a.z, a.w};
                    const float bv[8] = {b0.x, b0.y, b0.z, b0.w, b1.x, b1.y, b1.z, b1.w};
                    #pragma unroll
                    for (int i = 0; i < 4; ++i)
                        #pragma unroll
                        for (int j = 0; j < 8; ++j)
                            lg[i][cb * 8 + j] = fmaf(av[i], bv[j], lg[i][cb * 8 + j]);
                }
            }
            __syncthreads();
        }
    }

    // ---- bias + gumbel (tau = 1.0); col(cb,j) = cb*256 + (j>>2)*128 + 4*tc + (j&3)
    #pragma unroll
    for (int cb = 0; cb < NCB; ++cb) {
        const int cbase = cb * NB + 4 * tc;
        const float4 bb0 = *(const float4*)(bias + cbase);
        const float4 bb1 = *(const float4*)(bias + cbase + 128);
        #pragma unroll
        for (int i = 0; i < 4; ++i) {
            const int row = row0 + 4 * tr + i;
            const float4 g0 = *(const float4*)(gum + (size_t)row * KK + cbase);
            const float4 g1 = *(const float4*)(gum + (size_t)row * KK + cbase + 128);
            lg[i][cb * 8 + 0] += bb0.x + g0.x;
            lg[i][cb * 8 + 1] += bb0.y + g0.y;
            lg[i][cb * 8 + 2] += bb0.z + g0.z;
            lg[i][cb * 8 + 3] += bb0.w + g0.w;
            lg[i][cb * 8 + 4] += bb1.x + g1.x;
            lg[i][cb * 8 + 5] += bb1.y + g1.y;
            lg[i][cb * 8 + 6] += bb1.z + g1.z;
            lg[i][cb * 8 + 7] += bb1.w + g1.w;
        }
    }

    // ---- per-row: argmax (first-occurrence tie-break), softmax, z_q gather, m
    #pragma unroll
    for (int i = 0; i < 4; ++i) {
        float mv = -1e30f; int mi = 0;
        #pragma unroll
        for (int t = 0; t < 32; ++t) {
            const int c = (t >> 3) * NB + ((t >> 2) & 1) * 128 + 4 * tc + (t & 3);
            if (lg[i][t] > mv) { mv = lg[i][t]; mi = c; }
        }
        #pragma unroll
        for (int off = 1; off < 32; off <<= 1) {
            const float ov = __shfl_xor(mv, off);
            const int   oi = __shfl_xor(mi, off);
            if (ov > mv || (ov == mv && oi < mi)) { mv = ov; mi = oi; }
        }
        float s = 0.f;
        #pragma unroll
        for (int t = 0; t < 32; ++t) {
            const float e = __expf(lg[i][t] - mv);
            lg[i][t] = e;
            s += e;
        }
        #pragma unroll
        for (int off = 1; off < 32; off <<= 1) s += __shfl_xor(s, off);
        const float rinv = 1.f / s;
        #pragma unroll
        for (int t = 0; t < 32; ++t) lg[i][t] *= rinv;

        const int row = row0 + 4 * tr + i;
        // z_q[row] = codebook[argmax]; contiguous 16B per lane -> coalesced
        const float4 c0 = *(const float4*)(cbk + (size_t)mi * EE + 4 * tc);
        const float4 c1 = *(const float4*)(cbk + (size_t)mi * EE + 4 * tc + 128);
        *(float4*)(out + (size_t)row * EE + 4 * tc)       = c0;
        *(float4*)(out + (size_t)row * EE + 4 * tc + 128) = c1;
        if (tc == 0) out[(size_t)BT * EE + row] = (float)mi;
    }

    // ---- avg_p partials: block-local LDS accumulate, then 1 global atomic/col
    #pragma unroll
    for (int t = 0; t < 32; ++t) lg[0][t] += lg[1][t] + lg[2][t] + lg[3][t];
    __syncthreads();
    float* aggp = smem;
    for (int q = tid; q < KK; q += 256) aggp[q] = 0.f;
    __syncthreads();
    #pragma unroll
    for (int t = 0; t < 32; ++t) {
        const int c = (t >> 3) * NB + ((t >> 2) & 1) * 128 + 4 * tc + (t & 3);
        atomicAdd(&aggp[c], lg[0][t]);
    }
    __syncthreads();
    for (int q = tid; q < KK; q += 256) atomicAdd(&gsum[q], aggp[q]);
}

__global__ void vq_fin(const float* __restrict__ gsum, float* __restrict__ out) {
    __shared__ float red[4];
    const int tid = threadIdx.x;
    float local = 0.f;
    for (int q = tid; q < KK; q += 256) {
        const float a = gsum[q] * (1.0f / (float)BT);
        local += a * (logf(fmaxf(a, 1e-9f)) + LOGK);
    }
    #pragma unroll
    for (int off = 1; off < 64; off <<= 1) local += __shfl_xor(local, off);
    if ((tid & 63) == 0) red[tid >> 6] = local;
    __syncthreads();
    if (tid == 0) {
        out[(size_t)BT * EE + BT]     = red[0] + red[1] + red[2] + red[3];
        out[(size_t)BT * EE + BT + 1] = 0.f;
    }
}

extern "C" void kernel_launch(void* const* d_in, const int* in_sizes, int n_in,
                              void* d_out, int out_size, void* d_ws, size_t ws_size,
                              hipStream_t stream) {
    const float* x   = (const float*)d_in[0];
    const float* g   = (const float*)d_in[1];
    const float* W   = (const float*)d_in[2];
    const float* b   = (const float*)d_in[3];
    const float* cbk = (const float*)d_in[4];
    float* out  = (float*)d_out;
    float* gsum = (float*)d_ws;

    hipMemsetAsync(gsum, 0, KK * sizeof(float), stream);
    vq_main<<<BT / MT, 256, 0, stream>>>(x, g, W, b, cbk, out, gsum);
    vq_fin<<<1, 256, 0, stream>>>(gsum, out);
}